// Round 11
// baseline (160.028 us; speedup 1.0000x reference)
//
#include <hip/hip_runtime.h>
#include <hip/hip_bf16.h>

typedef int    i32x4 __attribute__((ext_vector_type(4)));
typedef float  f32x4 __attribute__((ext_vector_type(4)));

#define NPIX  100352   // 32*56*56
#define CIN   256
#define COUT  256

#define QC    4.75f
#define QINV  (127.0f/QC)
#define QDEQ  (QC/127.0f)

#define WBT_OFF 0u
#define XQ_OFF  (1024u*1024u)
#define WS_NEED_I8 ((size_t)XQ_OFF + (size_t)32*3364*256)   // ~28.6 MB

#define BAR() do { asm volatile("" ::: "memory"); __builtin_amdgcn_s_barrier(); asm volatile("" ::: "memory"); } while(0)

// ---- merged prepass: blocks [0,13456) quantize+pad x; blocks [13456,15760) binarize w ----
__global__ __launch_bounds__(256) void prep_kernel(const float* __restrict__ x,
                                                   signed char* __restrict__ xq,
                                                   const float* __restrict__ w,
                                                   signed char* __restrict__ wbt) {
    const int bid = blockIdx.x;
    if (bid < 13456) {
        const int g = bid * 256 + threadIdx.x;          // chunk of 8 channels
        const int prow = g >> 5, cseg = g & 31;
        const int b = prow / 3364, rr = prow % 3364;
        const int ph = rr / 58, pw = rr % 58;
        int2 pack = {0, 0};
        if (ph >= 1 && ph <= 56 && pw >= 1 && pw <= 56) {
            const size_t s = ((size_t)b * 3136 + (size_t)(ph - 1) * 56 + (pw - 1)) * 256 + cseg * 8;
            const f32x4 a = *(const f32x4*)(x + s);
            const f32x4 c = *(const f32x4*)(x + s + 4);
            unsigned lo = 0, hi = 0;
            #pragma unroll
            for (int j = 0; j < 4; ++j) {
                int qa = (int)rintf(fminf(fmaxf(a[j], -QC), QC) * QINV);
                int qc = (int)rintf(fminf(fmaxf(c[j], -QC), QC) * QINV);
                lo |= (unsigned)(qa & 255) << (8 * j);
                hi |= (unsigned)(qc & 255) << (8 * j);
            }
            pack.x = (int)lo; pack.y = (int)hi;
        }
        *(int2*)(xq + (size_t)g * 8) = pack;
    } else {
        const int rc   = bid - 13456;                   // tap*256 + cin
        const int cout = threadIdx.x;
        const float v  = w[(size_t)rc * COUT + cout];
        const signed char s = (v > 0.f) ? 1 : ((v < 0.f) ? -1 : 0);
        const int tap = rc >> 8;
        const int cin = rc & 255;
        wbt[((size_t)(tap * COUT + cout)) * CIN + cin] = s;
    }
}

__device__ __forceinline__ void gll16(const signed char* g, signed char* l) {
    __builtin_amdgcn_global_load_lds(
        (const __attribute__((address_space(1))) void*)g,
        (__attribute__((address_space(3))) void*)l, 16, 0, 0);
}

__device__ __forceinline__ void mfma_i8(i32x4& acc, i32x4 a, i32x4 b) {
    asm("v_mfma_i32_16x16x64_i8 %0, %1, %2, %0" : "+v"(acc) : "v"(a), "v"(b));
}

// =====  128x128 i8 kernel: A via LDS (round-6 geometry), B via register dbuf  =====
// LDS: A0, A1 only — 128 rows x 128 B each = 32 KB total.
#define SA0 0
#define SA1 16384

#define STAGE_A(REG, TS) do {                                                        \
    const int tap_ = (TS) >> 1;                                                      \
    const int dh1_ = (tap_ * 11) >> 5;  /* tap/3 */                                  \
    const int off_ = ((dh1_ - 1) * 58 + (tap_ - dh1_ * 3 - 1)) * 256 + (((TS) & 1) << 7); \
    _Pragma("unroll")                                                                \
    for (int j_ = 0; j_ < 4; ++j_) gll16(pA[j_] + off_, &lds[(REG) + dOf[j_]]);      \
} while (0)

// load B k-quarter kq of K-step TS into frag slots dst[kq*4 .. kq*4+3]
#define LDB(DST, TS, KQ) do {                                                        \
    const signed char* p_ = bbase + (((TS) >> 1) << 16) + (((TS) & 1) << 7) + ((KQ) << 6); \
    _Pragma("unroll")                                                                \
    for (int f_ = 0; f_ < 4; ++f_) (DST)[(KQ) * 4 + f_] = *(const i32x4*)(p_ + f_ * 4096); \
} while (0)

__global__ __launch_bounds__(256, 2) void conv4i(const signed char* __restrict__ xq,
                                                 const signed char* __restrict__ wbt,
                                                 float* __restrict__ out) {
    __shared__ signed char lds[32768];

    const int tid  = threadIdx.x;
    const int lane = tid & 63;
    const int wave = tid >> 6;                  // 0..3
    const int l3 = lane >> 3, l7 = lane & 7;
    const int srcslot = l7 ^ l3;                // source swizzle involution (8 slots x 16B)
    const int lr = lane & 15, kseg = lane >> 4;

    // 1568 blocks = 8 XCD chunks x 196; chunked bijective swizzle
    const int bid = blockIdx.x;
    const int L   = (bid & 7) * 196 + (bid >> 3);
    const int bm  = L >> 1;                     // 0..783 (128-pixel tile)
    const int bn  = L & 1;                      // 0..1   (128-cout tile)

    // ---- A staging geometry: wave w owns rows w*32..+31, 4 issues of 8 rows ----
    const signed char* pA[4];
    int dOf[4];
    #pragma unroll
    for (int j = 0; j < 4; ++j) {
        const int rb = wave * 32 + j * 8;
        dOf[j] = rb * 128;                      // wave-uniform LDS byte offset
        const int r = rb + l3;                  // per-lane row
        const int p = bm * 128 + r;
        const int b = p / 3136, rem = p % 3136;
        const int hh = rem / 56, ww = rem % 56;
        pA[j] = xq + ((size_t)b * 3364 + (size_t)(hh + 1) * 58 + (ww + 1)) * 256
                   + srcslot * 16;
    }

    // ---- A frag read byte offsets (within each 128x128B region) ----
    const int m_base = (wave >> 1) * 64;
    const int n_base = (wave & 1) * 64;
    const int slot0 = ((kseg)     ^ (lr & 7)) * 16;
    const int slot1 = ((4 + kseg) ^ (lr & 7)) * 16;
    const int aB = (m_base + lr) * 128;
    const int aK0 = aB + slot0, aK1 = aB + slot1;

    // ---- B per-lane base: cout row (bn*128 + n_base + f*16 + lr), 16B chunk kseg ----
    const signed char* bbase = wbt + (size_t)(bn * 128 + n_base + lr) * 256 + kseg * 16;

    i32x4 acc[4][4];
    #pragma unroll
    for (int f = 0; f < 4; ++f)
        #pragma unroll
        for (int n = 0; n < 4; ++n)
            acc[f][n] = (i32x4){0, 0, 0, 0};

    i32x4 Bc[8], Bn[8];   // B register double-buffer: even steps use Bc, odd use Bn

    // ---- prologue: A(0)->SA0, B(0)->Bc; full drain once (order-safe) ----
    STAGE_A(SA0, 0);
    LDB(Bc, 0, 0);
    LDB(Bc, 0, 1);
    asm volatile("s_waitcnt vmcnt(0)" ::: "memory");
    BAR();

    // 9 iterations; iter i = steps 2i (SA0,Bc) and 2i+1 (SA1,Bn).
    // Mixed vmcnt ledger (FIFO-verified, order-insensitive within phases):
    //   ph1-end vmcnt(8): drains B.k1(ts) needed by ph2; keeps {B.k0(ts+1), A(ts+1)}.
    //   ph2-end vmcnt(4): drains {B.k0(ts+1), A(ts+1)}; keeps B.k1(ts+1) in flight.
    for (int i = 0; i < 9; ++i) {
        const bool last = (i == 8);

        // ===== step ts=2i : A in SA0, B in Bc; prefetch ts+1 -> SA1, Bn =====
        {
            const int tn = 2 * i + 1;
            // --- phase k0 ---
            i32x4 af[4];
            #pragma unroll
            for (int f = 0; f < 4; ++f) af[f] = *(const i32x4*)&lds[SA0 + aK0 + f * 2048];
            LDB(Bn, tn, 0);
            STAGE_A(SA1, tn);
            asm volatile("s_waitcnt vmcnt(8)" ::: "memory");
            __builtin_amdgcn_s_setprio(1);
            #pragma unroll
            for (int f = 0; f < 4; ++f)
                #pragma unroll
                for (int n = 0; n < 4; ++n) mfma_i8(acc[f][n], af[f], Bc[n]);
            __builtin_amdgcn_s_setprio(0);
            BAR();
            // --- phase k1 ---
            #pragma unroll
            for (int f = 0; f < 4; ++f) af[f] = *(const i32x4*)&lds[SA0 + aK1 + f * 2048];
            LDB(Bn, tn, 1);
            asm volatile("s_waitcnt vmcnt(4)" ::: "memory");
            __builtin_amdgcn_s_setprio(1);
            #pragma unroll
            for (int f = 0; f < 4; ++f)
                #pragma unroll
                for (int n = 0; n < 4; ++n) mfma_i8(acc[f][n], af[f], Bc[4 + n]);
            __builtin_amdgcn_s_setprio(0);
            BAR();
        }

        // ===== step ts=2i+1 : A in SA1, B in Bn; prefetch ts+1 -> SA0, Bc =====
        {
            const int tn = 2 * i + 2;
            // --- phase k0 ---
            i32x4 af[4];
            #pragma unroll
            for (int f = 0; f < 4; ++f) af[f] = *(const i32x4*)&lds[SA1 + aK0 + f * 2048];
            if (!last) {
                LDB(Bc, tn, 0);
                STAGE_A(SA0, tn);
                asm volatile("s_waitcnt vmcnt(8)" ::: "memory");
            } else {
                asm volatile("s_waitcnt vmcnt(0)" ::: "memory");
            }
            __builtin_amdgcn_s_setprio(1);
            #pragma unroll
            for (int f = 0; f < 4; ++f)
                #pragma unroll
                for (int n = 0; n < 4; ++n) mfma_i8(acc[f][n], af[f], Bn[n]);
            __builtin_amdgcn_s_setprio(0);
            BAR();
            // --- phase k1 ---
            #pragma unroll
            for (int f = 0; f < 4; ++f) af[f] = *(const i32x4*)&lds[SA1 + aK1 + f * 2048];
            if (!last) {
                LDB(Bc, tn, 1);
                asm volatile("s_waitcnt vmcnt(4)" ::: "memory");
            }
            __builtin_amdgcn_s_setprio(1);
            #pragma unroll
            for (int f = 0; f < 4; ++f)
                #pragma unroll
                for (int n = 0; n < 4; ++n) mfma_i8(acc[f][n], af[f], Bn[4 + n]);
            __builtin_amdgcn_s_setprio(0);
            BAR();
        }
    }

    // ---- epilogue: C/D map col=lane&15, row=(lane>>4)*4+j; dequant ----
    const int row0 = bm * 128 + m_base + (lane >> 4) * 4;
    const int col0 = bn * 128 + n_base + lr;
    #pragma unroll
    for (int f = 0; f < 4; ++f)
        #pragma unroll
        for (int n = 0; n < 4; ++n) {
            const int r = row0 + f * 16;
            const int c = col0 + n * 16;
            #pragma unroll
            for (int j = 0; j < 4; ++j)
                out[(size_t)(r + j) * COUT + c] = QDEQ * (float)acc[f][n][j];
        }
}

// =====================  fallback (tiny ws): bf16 reg-staged  =====================
__global__ void binw_bf16(const float* __restrict__ w, __bf16* __restrict__ wbt) {
    const int cout = threadIdx.x;
    const int rc   = blockIdx.x;
    const float v  = w[(size_t)rc * COUT + cout];
    const float s  = (v > 0.f) ? 1.f : ((v < 0.f) ? -1.f : 0.f);
    wbt[((size_t)((rc >> 8) * COUT + cout)) * CIN + (rc & 255)] = (__bf16)s;
}

__global__ __launch_bounds__(512) void conv_fb(const float* __restrict__ x,
                                               const __bf16* __restrict__ wbt,
                                               float* __restrict__ out) {
    __shared__ __bf16 Alds[128][72];
    __shared__ __bf16 Blds[256][72];
    typedef __bf16 bf8 __attribute__((ext_vector_type(8)));

    const int tid  = threadIdx.x;
    const int lane = tid & 63;
    const int wave = tid >> 6;
    const int m_base = (wave >> 2) * 64;
    const int n_base = (wave & 3) * 64;
    const int lr = lane & 15;
    const int kb = (lane >> 4) * 8;

    const int arow = tid >> 2;
    const int aseg = tid & 3;
    const int p    = blockIdx.x * 128 + arow;
    const int rem  = p % 3136;
    const int h    = rem / 56;
    const int wc   = rem % 56;

    f32x4 acc[4][4];
    #pragma unroll
    for (int i = 0; i < 4; ++i)
        #pragma unroll
        for (int j = 0; j < 4; ++j)
            acc[i][j] = (f32x4){0.f, 0.f, 0.f, 0.f};

    for (int tap = 0; tap < 9; ++tap) {
        const int dh = tap / 3 - 1;
        const int dw = tap % 3 - 1;
        const bool valid = ((unsigned)(h + dh) < 56u) && ((unsigned)(wc + dw) < 56u);
        const long aoff = ((long)p + (long)dh * 56 + dw) * CIN + aseg * 16;
        const __bf16* bsrc = wbt + (size_t)tap * COUT * CIN;

        #pragma unroll
        for (int ks = 0; ks < 4; ++ks) {
            const int c0 = ks * 64;
            __syncthreads();
            f32x4 f0, f1, f2, f3;
            if (valid) {
                const f32x4* s4 = (const f32x4*)(x + aoff + c0);
                f0 = s4[0]; f1 = s4[1]; f2 = s4[2]; f3 = s4[3];
            } else {
                f0 = f1 = f2 = f3 = (f32x4){0.f, 0.f, 0.f, 0.f};
            }
            bf8 v0, v1;
            #pragma unroll
            for (int j = 0; j < 4; ++j) {
                v0[j] = (__bf16)f0[j]; v0[j + 4] = (__bf16)f1[j];
                v1[j] = (__bf16)f2[j]; v1[j + 4] = (__bf16)f3[j];
            }
            *(bf8*)&Alds[arow][aseg * 16]     = v0;
            *(bf8*)&Alds[arow][aseg * 16 + 8] = v1;
            #pragma unroll
            for (int i = 0; i < 4; ++i) {
                const int chunk = tid + i * 512;
                const int row = chunk >> 3;
                const int cs  = chunk & 7;
                *(uint4*)&Blds[row][cs * 8] = *(const uint4*)(bsrc + row * CIN + c0 + cs * 8);
            }
            __syncthreads();

            bf8 af[4][2], bfr[4][2];
            #pragma unroll
            for (int mf = 0; mf < 4; ++mf)
                #pragma unroll
                for (int kf = 0; kf < 2; ++kf)
                    af[mf][kf] = *(const bf8*)&Alds[m_base + mf * 16 + lr][kf * 32 + kb];
            #pragma unroll
            for (int nf = 0; nf < 4; ++nf)
                #pragma unroll
                for (int kf = 0; kf < 2; ++kf)
                    bfr[nf][kf] = *(const bf8*)&Blds[n_base + nf * 16 + lr][kf * 32 + kb];
            #pragma unroll
            for (int kf = 0; kf < 2; ++kf)
                #pragma unroll
                for (int mf = 0; mf < 4; ++mf)
                    #pragma unroll
                    for (int nf = 0; nf < 4; ++nf)
                        acc[mf][nf] = __builtin_amdgcn_mfma_f32_16x16x32_bf16(
                            af[mf][kf], bfr[nf][kf], acc[mf][nf], 0, 0, 0);
        }
    }
    #pragma unroll
    for (int mf = 0; mf < 4; ++mf)
        #pragma unroll
        for (int nf = 0; nf < 4; ++nf) {
            const int r0 = blockIdx.x * 128 + m_base + mf * 16 + (lane >> 4) * 4;
            const int c  = n_base + nf * 16 + lr;
            #pragma unroll
            for (int j = 0; j < 4; ++j)
                out[(size_t)(r0 + j) * COUT + c] = acc[mf][nf][j];
        }
}

extern "C" void kernel_launch(void* const* d_in, const int* in_sizes, int n_in,
                              void* d_out, int out_size, void* d_ws, size_t ws_size,
                              hipStream_t stream) {
    const float* x = (const float*)d_in[0];
    const float* w = (const float*)d_in[1];
    float* out = (float*)d_out;
    char* ws = (char*)d_ws;

    if (ws_size >= WS_NEED_I8) {
        signed char* wbt = (signed char*)(ws + WBT_OFF);
        signed char* xq  = (signed char*)(ws + XQ_OFF);
        prep_kernel<<<13456 + 2304, 256, 0, stream>>>(x, xq, w, wbt);
        conv4i<<<1568, 256, 0, stream>>>(xq, wbt, out);
    } else {
        __bf16* wbt = (__bf16*)(ws + WBT_OFF);
        binw_bf16<<<9 * CIN, COUT, 0, stream>>>(w, wbt);
        conv_fb<<<NPIX / 128, 512, 0, stream>>>(x, wbt, out);
    }
}

// Round 12
// 160.027 us; speedup vs baseline: 1.0000x; 1.0000x over previous
//
#include <hip/hip_runtime.h>
#include <hip/hip_bf16.h>

typedef int    i32x4 __attribute__((ext_vector_type(4)));
typedef float  f32x4 __attribute__((ext_vector_type(4)));

#define NPIX  100352   // 32*56*56
#define CIN   256
#define COUT  256

#define QC    4.75f
#define QINV  (127.0f/QC)
#define QDEQ  (QC/127.0f)

#define WBT_OFF 0u
#define XQ_OFF  (1024u*1024u)
#define WS_NEED_I8 ((size_t)XQ_OFF + (size_t)32*3364*256)   // ~28.6 MB

#define BAR() do { asm volatile("" ::: "memory"); __builtin_amdgcn_s_barrier(); asm volatile("" ::: "memory"); } while(0)

// ---- merged prepass: blocks [0,13456) quantize+pad x; blocks [13456,15760) binarize w ----
__global__ __launch_bounds__(256) void prep_kernel(const float* __restrict__ x,
                                                   signed char* __restrict__ xq,
                                                   const float* __restrict__ w,
                                                   signed char* __restrict__ wbt) {
    const int bid = blockIdx.x;
    if (bid < 13456) {
        const int g = bid * 256 + threadIdx.x;          // chunk of 8 channels
        const int prow = g >> 5, cseg = g & 31;
        const int b = prow / 3364, rr = prow % 3364;
        const int ph = rr / 58, pw = rr % 58;
        int2 pack = {0, 0};
        if (ph >= 1 && ph <= 56 && pw >= 1 && pw <= 56) {
            const size_t s = ((size_t)b * 3136 + (size_t)(ph - 1) * 56 + (pw - 1)) * 256 + cseg * 8;
            const f32x4 a = *(const f32x4*)(x + s);
            const f32x4 c = *(const f32x4*)(x + s + 4);
            unsigned lo = 0, hi = 0;
            #pragma unroll
            for (int j = 0; j < 4; ++j) {
                int qa = (int)rintf(fminf(fmaxf(a[j], -QC), QC) * QINV);
                int qc = (int)rintf(fminf(fmaxf(c[j], -QC), QC) * QINV);
                lo |= (unsigned)(qa & 255) << (8 * j);
                hi |= (unsigned)(qc & 255) << (8 * j);
            }
            pack.x = (int)lo; pack.y = (int)hi;
        }
        *(int2*)(xq + (size_t)g * 8) = pack;
    } else {
        const int rc   = bid - 13456;                   // tap*256 + cin
        const int cout = threadIdx.x;
        const float v  = w[(size_t)rc * COUT + cout];
        const signed char s = (v > 0.f) ? 1 : ((v < 0.f) ? -1 : 0);
        const int tap = rc >> 8;
        const int cin = rc & 255;
        wbt[((size_t)(tap * COUT + cout)) * CIN + cin] = s;
    }
}

__device__ __forceinline__ void gll16(const signed char* g, signed char* l) {
    __builtin_amdgcn_global_load_lds(
        (const __attribute__((address_space(1))) void*)g,
        (__attribute__((address_space(3))) void*)l, 16, 0, 0);
}

__device__ __forceinline__ void mfma_i8(i32x4& acc, i32x4 a, i32x4 b) {
    asm("v_mfma_i32_16x16x64_i8 %0, %1, %2, %0" : "+v"(acc) : "v"(a), "v"(b));
}

// =====  128x128 i8: A via LDS (round-6 geometry), B in NAMED register dbuf  =====
// LDS: A0, A1 only — 128 rows x 128 B each = 32 KB total.
#define SA0 0
#define SA1 16384

#define STAGE_A(REG, TS) do {                                                        \
    const int tap_ = (TS) >> 1;                                                      \
    const int dh1_ = (tap_ * 11) >> 5;  /* tap/3 */                                  \
    const int off_ = ((dh1_ - 1) * 58 + (tap_ - dh1_ * 3 - 1)) * 256 + (((TS) & 1) << 7); \
    _Pragma("unroll")                                                                \
    for (int j_ = 0; j_ < 4; ++j_) gll16(pA[j_] + off_, &lds[(REG) + dOf[j_]]);      \
} while (0)

// load B quarter KQ of K-step TS into four NAMED regs (frag f at +f*4096B = f*16 rows)
#define LDB4(D0, D1, D2, D3, TS, KQ) do {                                            \
    const signed char* p_ = bbase + (((TS) >> 1) << 16) + (((TS) & 1) << 7) + ((KQ) << 6); \
    D0 = *(const i32x4*)(p_);                                                        \
    D1 = *(const i32x4*)(p_ + 4096);                                                 \
    D2 = *(const i32x4*)(p_ + 8192);                                                 \
    D3 = *(const i32x4*)(p_ + 12288);                                                \
} while (0)

// 16 MFMA: af[0..3] x (B0..B3) -> acc[f][n]
#define MFMA16(B0, B1, B2, B3) do {                                                  \
    __builtin_amdgcn_s_setprio(1);                                                   \
    _Pragma("unroll")                                                                \
    for (int f_ = 0; f_ < 4; ++f_) {                                                 \
        mfma_i8(acc[f_][0], af[f_], B0);                                             \
        mfma_i8(acc[f_][1], af[f_], B1);                                             \
        mfma_i8(acc[f_][2], af[f_], B2);                                             \
        mfma_i8(acc[f_][3], af[f_], B3);                                             \
    }                                                                                \
    __builtin_amdgcn_s_setprio(0);                                                   \
} while (0)

#define LDA(REG, AK) do {                                                            \
    _Pragma("unroll")                                                                \
    for (int f_ = 0; f_ < 4; ++f_) af[f_] = *(const i32x4*)&lds[(REG) + (AK) + f_ * 2048]; \
} while (0)

__global__ __launch_bounds__(256, 2) void conv4i(const signed char* __restrict__ xq,
                                                 const signed char* __restrict__ wbt,
                                                 float* __restrict__ out) {
    __shared__ signed char lds[32768];

    const int tid  = threadIdx.x;
    const int lane = tid & 63;
    const int wave = tid >> 6;                  // 0..3
    const int l3 = lane >> 3, l7 = lane & 7;
    const int srcslot = l7 ^ l3;                // source swizzle involution (8 slots x 16B)
    const int lr = lane & 15, kseg = lane >> 4;

    // 1568 blocks = 8 XCD chunks x 196; chunked bijective swizzle
    const int bid = blockIdx.x;
    const int L   = (bid & 7) * 196 + (bid >> 3);
    const int bm  = L >> 1;                     // 0..783 (128-pixel tile)
    const int bn  = L & 1;                      // 0..1   (128-cout tile)

    // ---- A staging geometry: wave w owns rows w*32..+31, 4 issues of 8 rows ----
    const signed char* pA[4];
    int dOf[4];
    #pragma unroll
    for (int j = 0; j < 4; ++j) {
        const int rb = wave * 32 + j * 8;
        dOf[j] = rb * 128;                      // wave-uniform LDS byte offset
        const int r = rb + l3;                  // per-lane row
        const int p = bm * 128 + r;
        const int b = p / 3136, rem = p % 3136;
        const int hh = rem / 56, ww = rem % 56;
        pA[j] = xq + ((size_t)b * 3364 + (size_t)(hh + 1) * 58 + (ww + 1)) * 256
                   + srcslot * 16;
    }

    // ---- A frag read byte offsets (within each 128x128B region) ----
    const int m_base = (wave >> 1) * 64;
    const int n_base = (wave & 1) * 64;
    const int slot0 = ((kseg)     ^ (lr & 7)) * 16;
    const int slot1 = ((4 + kseg) ^ (lr & 7)) * 16;
    const int aB = (m_base + lr) * 128;
    const int aK0 = aB + slot0, aK1 = aB + slot1;

    // ---- B per-lane base: row (bn*128 + n_base + f*16 + lr), chunk kseg ----
    const signed char* bbase = wbt + (size_t)(bn * 128 + n_base + lr) * 256 + kseg * 16;

    i32x4 acc[4][4];
    #pragma unroll
    for (int f = 0; f < 4; ++f)
        #pragma unroll
        for (int n = 0; n < 4; ++n)
            acc[f][n] = (i32x4){0, 0, 0, 0};

    // B register double-buffer: NAMED vars only (arrays spilled to scratch in R11)
    i32x4 Bc0, Bc1, Bc2, Bc3, Bc4, Bc5, Bc6, Bc7;   // even steps consume
    i32x4 Bn0, Bn1, Bn2, Bn3, Bn4, Bn5, Bn6, Bn7;   // odd steps consume
    i32x4 af[4];

    // ---- prologue: A(0)->SA0 (4 gll), B(0)->Bc (8 loads); drain A only ----
    STAGE_A(SA0, 0);
    LDB4(Bc0, Bc1, Bc2, Bc3, 0, 0);
    LDB4(Bc4, Bc5, Bc6, Bc7, 0, 1);
    asm volatile("s_waitcnt vmcnt(8)" ::: "memory");   // A(0) landed; Bc compiler-tracked
    BAR();

    // FIFO-simulated ledger: one manual vmcnt(4) per K-step (k1-end) drains
    // {B-k0(next), A(next)} and leaves B-k1(next) in flight. B register RAW is
    // compiler-tracked. WAR: SA_x restaged >=1 barrier after its last ds_read.
    for (int i = 0; i < 9; ++i) {
        const bool last = (i == 8);

        // ===== step 2i (SA0, Bc); prefetch step 2i+1 -> SA1, Bn =====
        {
            const int tn = 2 * i + 1;
            // --- k0 ---
            LDA(SA0, aK0);
            LDB4(Bn0, Bn1, Bn2, Bn3, tn, 0);
            STAGE_A(SA1, tn);
            MFMA16(Bc0, Bc1, Bc2, Bc3);
            BAR();
            // --- k1 ---
            LDA(SA0, aK1);
            LDB4(Bn4, Bn5, Bn6, Bn7, tn, 1);
            MFMA16(Bc4, Bc5, Bc6, Bc7);
            asm volatile("s_waitcnt vmcnt(4)" ::: "memory");  // drains Bn-k0 + A(tn); Bn-k1 flies
            BAR();
        }

        // ===== step 2i+1 (SA1, Bn); prefetch step 2i+2 -> SA0, Bc =====
        {
            const int tn = 2 * i + 2;
            // --- k0 ---
            LDA(SA1, aK0);
            if (!last) {
                LDB4(Bc0, Bc1, Bc2, Bc3, tn, 0);
                STAGE_A(SA0, tn);
            }
            MFMA16(Bn0, Bn1, Bn2, Bn3);
            BAR();
            // --- k1 ---
            LDA(SA1, aK1);
            if (!last) {
                LDB4(Bc4, Bc5, Bc6, Bc7, tn, 1);
                MFMA16(Bn4, Bn5, Bn6, Bn7);
                asm volatile("s_waitcnt vmcnt(4)" ::: "memory");  // drains Bc-k0 + A(tn)
            } else {
                MFMA16(Bn4, Bn5, Bn6, Bn7);
                asm volatile("s_waitcnt vmcnt(0)" ::: "memory");
            }
            BAR();
        }
    }

    // ---- epilogue: C/D map col=lane&15, row=(lane>>4)*4+j; dequant ----
    const int row0 = bm * 128 + m_base + (lane >> 4) * 4;
    const int col0 = bn * 128 + n_base + lr;
    #pragma unroll
    for (int f = 0; f < 4; ++f)
        #pragma unroll
        for (int n = 0; n < 4; ++n) {
            const int r = row0 + f * 16;
            const int c = col0 + n * 16;
            #pragma unroll
            for (int j = 0; j < 4; ++j)
                out[(size_t)(r + j) * COUT + c] = QDEQ * (float)acc[f][n][j];
        }
}

// =====================  fallback (tiny ws): bf16 reg-staged  =====================
__global__ void binw_bf16(const float* __restrict__ w, __bf16* __restrict__ wbt) {
    const int cout = threadIdx.x;
    const int rc   = blockIdx.x;
    const float v  = w[(size_t)rc * COUT + cout];
    const float s  = (v > 0.f) ? 1.f : ((v < 0.f) ? -1.f : 0.f);
    wbt[((size_t)((rc >> 8) * COUT + cout)) * CIN + (rc & 255)] = (__bf16)s;
}

__global__ __launch_bounds__(512) void conv_fb(const float* __restrict__ x,
                                               const __bf16* __restrict__ wbt,
                                               float* __restrict__ out) {
    __shared__ __bf16 Alds[128][72];
    __shared__ __bf16 Blds[256][72];
    typedef __bf16 bf8 __attribute__((ext_vector_type(8)));

    const int tid  = threadIdx.x;
    const int lane = tid & 63;
    const int wave = tid >> 6;
    const int m_base = (wave >> 2) * 64;
    const int n_base = (wave & 3) * 64;
    const int lr = lane & 15;
    const int kb = (lane >> 4) * 8;

    const int arow = tid >> 2;
    const int aseg = tid & 3;
    const int p    = blockIdx.x * 128 + arow;
    const int rem  = p % 3136;
    const int h    = rem / 56;
    const int wc   = rem % 56;

    f32x4 acc[4][4];
    #pragma unroll
    for (int i = 0; i < 4; ++i)
        #pragma unroll
        for (int j = 0; j < 4; ++j)
            acc[i][j] = (f32x4){0.f, 0.f, 0.f, 0.f};

    for (int tap = 0; tap < 9; ++tap) {
        const int dh = tap / 3 - 1;
        const int dw = tap % 3 - 1;
        const bool valid = ((unsigned)(h + dh) < 56u) && ((unsigned)(wc + dw) < 56u);
        const long aoff = ((long)p + (long)dh * 56 + dw) * CIN + aseg * 16;
        const __bf16* bsrc = wbt + (size_t)tap * COUT * CIN;

        #pragma unroll
        for (int ks = 0; ks < 4; ++ks) {
            const int c0 = ks * 64;
            __syncthreads();
            f32x4 f0, f1, f2, f3;
            if (valid) {
                const f32x4* s4 = (const f32x4*)(x + aoff + c0);
                f0 = s4[0]; f1 = s4[1]; f2 = s4[2]; f3 = s4[3];
            } else {
                f0 = f1 = f2 = f3 = (f32x4){0.f, 0.f, 0.f, 0.f};
            }
            bf8 v0, v1;
            #pragma unroll
            for (int j = 0; j < 4; ++j) {
                v0[j] = (__bf16)f0[j]; v0[j + 4] = (__bf16)f1[j];
                v1[j] = (__bf16)f2[j]; v1[j + 4] = (__bf16)f3[j];
            }
            *(bf8*)&Alds[arow][aseg * 16]     = v0;
            *(bf8*)&Alds[arow][aseg * 16 + 8] = v1;
            #pragma unroll
            for (int i = 0; i < 4; ++i) {
                const int chunk = tid + i * 512;
                const int row = chunk >> 3;
                const int cs  = chunk & 7;
                *(uint4*)&Blds[row][cs * 8] = *(const uint4*)(bsrc + row * CIN + c0 + cs * 8);
            }
            __syncthreads();

            bf8 af[4][2], bfr[4][2];
            #pragma unroll
            for (int mf = 0; mf < 4; ++mf)
                #pragma unroll
                for (int kf = 0; kf < 2; ++kf)
                    af[mf][kf] = *(const bf8*)&Alds[m_base + mf * 16 + lr][kf * 32 + kb];
            #pragma unroll
            for (int nf = 0; nf < 4; ++nf)
                #pragma unroll
                for (int kf = 0; kf < 2; ++kf)
                    bfr[nf][kf] = *(const bf8*)&Blds[n_base + nf * 16 + lr][kf * 32 + kb];
            #pragma unroll
            for (int kf = 0; kf < 2; ++kf)
                #pragma unroll
                for (int mf = 0; mf < 4; ++mf)
                    #pragma unroll
                    for (int nf = 0; nf < 4; ++nf)
                        acc[mf][nf] = __builtin_amdgcn_mfma_f32_16x16x32_bf16(
                            af[mf][kf], bfr[nf][kf], acc[mf][nf], 0, 0, 0);
        }
    }
    #pragma unroll
    for (int mf = 0; mf < 4; ++mf)
        #pragma unroll
        for (int nf = 0; nf < 4; ++nf) {
            const int r0 = blockIdx.x * 128 + m_base + mf * 16 + (lane >> 4) * 4;
            const int c  = n_base + nf * 16 + lr;
            #pragma unroll
            for (int j = 0; j < 4; ++j)
                out[(size_t)(r0 + j) * COUT + c] = acc[mf][nf][j];
        }
}

extern "C" void kernel_launch(void* const* d_in, const int* in_sizes, int n_in,
                              void* d_out, int out_size, void* d_ws, size_t ws_size,
                              hipStream_t stream) {
    const float* x = (const float*)d_in[0];
    const float* w = (const float*)d_in[1];
    float* out = (float*)d_out;
    char* ws = (char*)d_ws;

    if (ws_size >= WS_NEED_I8) {
        signed char* wbt = (signed char*)(ws + WBT_OFF);
        signed char* xq  = (signed char*)(ws + XQ_OFF);
        prep_kernel<<<13456 + 2304, 256, 0, stream>>>(x, xq, w, wbt);
        conv4i<<<1568, 256, 0, stream>>>(xq, wbt, out);
    } else {
        __bf16* wbt = (__bf16*)(ws + WBT_OFF);
        binw_bf16<<<9 * CIN, COUT, 0, stream>>>(w, wbt);
        conv_fb<<<NPIX / 128, 512, 0, stream>>>(x, wbt, out);
    }
}

// Round 13
// 89.552 us; speedup vs baseline: 1.7870x; 1.7870x over previous
//
#include <hip/hip_runtime.h>
#include <hip/hip_bf16.h>

typedef int    i32x4 __attribute__((ext_vector_type(4)));
typedef float  f32x4 __attribute__((ext_vector_type(4)));

#define NPIX  100352   // 32*56*56
#define CIN   256
#define COUT  256

#define QC    4.75f
#define QINV  (127.0f/QC)
#define QDEQ  (QC/127.0f)

#define WBT_OFF 0u
#define XQ_OFF  (1024u*1024u)
#define WS_NEED_I8 ((size_t)XQ_OFF + (size_t)32*3364*256)   // ~28.6 MB

#define BAR() do { asm volatile("" ::: "memory"); __builtin_amdgcn_s_barrier(); asm volatile("" ::: "memory"); } while(0)

// ---- merged prepass: blocks [0,13456) quantize+pad x; blocks [13456,15760) binarize w ----
__global__ __launch_bounds__(256) void prep_kernel(const float* __restrict__ x,
                                                   signed char* __restrict__ xq,
                                                   const float* __restrict__ w,
                                                   signed char* __restrict__ wbt) {
    const int bid = blockIdx.x;
    if (bid < 13456) {
        const int g = bid * 256 + threadIdx.x;          // chunk of 8 channels
        const int prow = g >> 5, cseg = g & 31;
        const int b = prow / 3364, rr = prow % 3364;
        const int ph = rr / 58, pw = rr % 58;
        int2 pack = {0, 0};
        if (ph >= 1 && ph <= 56 && pw >= 1 && pw <= 56) {
            const size_t s = ((size_t)b * 3136 + (size_t)(ph - 1) * 56 + (pw - 1)) * 256 + cseg * 8;
            const f32x4 a = *(const f32x4*)(x + s);
            const f32x4 c = *(const f32x4*)(x + s + 4);
            unsigned lo = 0, hi = 0;
            #pragma unroll
            for (int j = 0; j < 4; ++j) {
                int qa = (int)rintf(fminf(fmaxf(a[j], -QC), QC) * QINV);
                int qc = (int)rintf(fminf(fmaxf(c[j], -QC), QC) * QINV);
                lo |= (unsigned)(qa & 255) << (8 * j);
                hi |= (unsigned)(qc & 255) << (8 * j);
            }
            pack.x = (int)lo; pack.y = (int)hi;
        }
        *(int2*)(xq + (size_t)g * 8) = pack;
    } else {
        const int rc   = bid - 13456;                   // tap*256 + cin
        const int cout = threadIdx.x;
        const float v  = w[(size_t)rc * COUT + cout];
        const signed char s = (v > 0.f) ? 1 : ((v < 0.f) ? -1 : 0);
        const int tap = rc >> 8;
        const int cin = rc & 255;
        wbt[((size_t)(tap * COUT + cout)) * CIN + cin] = s;
    }
}

__device__ __forceinline__ void gll16(const signed char* g, signed char* l) {
    __builtin_amdgcn_global_load_lds(
        (const __attribute__((address_space(1))) void*)g,
        (__attribute__((address_space(3))) void*)l, 16, 0, 0);
}

__device__ __forceinline__ void mfma_i8(i32x4& acc, i32x4 a, i32x4 b) {
    asm("v_mfma_i32_16x16x64_i8 %0, %1, %2, %0" : "+v"(acc) : "v"(a), "v"(b));
}

// =====  4-phase 128x128 i8 kernel, BK=128, 2 blocks/CU (R10 base + k1-frag hoist)  =====
// LDS byte offsets: A0,B0,A1,B1 each 128 rows x 128 B = 16 KB (total 64 KB)
// Geometry (rows/slots/swizzle) IDENTICAL to the round-6/round-10 zero-conflict kernel.
#define SA0 0
#define SB0 16384
#define SA1 32768
#define SB1 49152

#define STAGE_A(REG, TS) do {                                                        \
    const int tap_ = (TS) >> 1;                                                      \
    const int dh1_ = (tap_ * 11) >> 5;  /* tap/3 */                                  \
    const int off_ = ((dh1_ - 1) * 58 + (tap_ - dh1_ * 3 - 1)) * 256 + (((TS) & 1) << 7); \
    _Pragma("unroll")                                                                \
    for (int j_ = 0; j_ < 4; ++j_) gll16(pA[j_] + off_, &lds[(REG) + dOf[j_]]);      \
} while (0)

#define STAGE_B(REG, TS) do {                                                        \
    const signed char* s_ = wbt + (((TS) >> 1) << 16) + (((TS) & 1) << 7);           \
    _Pragma("unroll")                                                                \
    for (int j_ = 0; j_ < 4; ++j_) gll16(s_ + bOf[j_], &lds[(REG) + dOf[j_]]);       \
} while (0)

__global__ __launch_bounds__(256, 2) void conv4i(const signed char* __restrict__ xq,
                                                 const signed char* __restrict__ wbt,
                                                 float* __restrict__ out) {
    __shared__ signed char lds[65536];

    const int tid  = threadIdx.x;
    const int lane = tid & 63;
    const int wave = tid >> 6;                  // 0..3
    const int l3 = lane >> 3, l7 = lane & 7;
    const int srcslot = l7 ^ l3;                // source swizzle involution (8 slots x 16B)
    const int lr = lane & 15, kseg = lane >> 4;

    // 1568 blocks = 8 XCD chunks x 196; chunked bijective swizzle
    const int bid = blockIdx.x;
    const int L   = (bid & 7) * 196 + (bid >> 3);
    const int bm  = L >> 1;                     // 0..783 (128-pixel tile)
    const int bn  = L & 1;                      // 0..1   (128-cout tile)

    // ---- staging geometry: wave w owns rows w*32..w*32+31, 4 issues of 8 rows ----
    const signed char* pA[4];
    int bOf[4], dOf[4];
    #pragma unroll
    for (int j = 0; j < 4; ++j) {
        const int rb = wave * 32 + j * 8;
        dOf[j] = rb * 128;                      // wave-uniform LDS byte offset
        const int r = rb + l3;                  // per-lane row
        bOf[j] = (bn * 128 + r) * 256 + srcslot * 16;
        const int p = bm * 128 + r;
        const int b = p / 3136, rem = p % 3136;
        const int hh = rem / 56, ww = rem % 56;
        pA[j] = xq + ((size_t)b * 3364 + (size_t)(hh + 1) * 58 + (ww + 1)) * 256
                   + srcslot * 16;
    }

    // ---- frag read byte offsets (within each 128x128B region) ----
    const int m_base = (wave >> 1) * 64;
    const int n_base = (wave & 1) * 64;
    const int slot0 = ((kseg)     ^ (lr & 7)) * 16;
    const int slot1 = ((4 + kseg) ^ (lr & 7)) * 16;
    const int aB = (m_base + lr) * 128;
    const int bB = (n_base + lr) * 128;
    const int aK0 = aB + slot0, aK1 = aB + slot1;
    const int bK0 = bB + slot0, bK1 = bB + slot1;

    i32x4 acc[4][4];
    #pragma unroll
    for (int f = 0; f < 4; ++f)
        #pragma unroll
        for (int n = 0; n < 4; ++n)
            acc[f][n] = (i32x4){0, 0, 0, 0};

    // ---- prologue: B0(0), A0(0), B1(1) = 12 issues; drain t0, keep B1 in flight ----
    STAGE_B(SB0, 0);
    STAGE_A(SA0, 0);
    STAGE_B(SB1, 1);
    asm volatile("s_waitcnt vmcnt(4)" ::: "memory");
    BAR();

    i32x4 bk0[4], bk1[4];
    i32x4 af[8];   // both k-halves of A, prefetched together (static indices only)

    // Ledger identical to R10 (FIFO-verified). Change vs R10: each odd phase's
    // A-frags (aK1) are read in the preceding even phase, hiding their LDS
    // latency under the even phase's 16 MFMAs.
    for (int i = 0; i < 9; ++i) {
        const bool last = (i == 8);
        const int te = 2 * i + 2;
        const int to = 2 * i + 3;

        // ===== ph1: read A(buf0, both kf) + all B(buf0); stage A1(2i+1); MFMA k0 =====
        {
            #pragma unroll
            for (int f = 0; f < 4; ++f) {
                af[f]     = *(const i32x4*)&lds[SA0 + aK0 + f * 2048];
                af[f + 4] = *(const i32x4*)&lds[SA0 + aK1 + f * 2048];
            }
            #pragma unroll
            for (int n = 0; n < 4; ++n) {
                bk0[n] = *(const i32x4*)&lds[SB0 + bK0 + n * 2048];
                bk1[n] = *(const i32x4*)&lds[SB0 + bK1 + n * 2048];
            }
            STAGE_A(SA1, 2 * i + 1);
            __builtin_amdgcn_s_setprio(1);
            #pragma unroll
            for (int f = 0; f < 4; ++f)
                #pragma unroll
                for (int n = 0; n < 4; ++n) mfma_i8(acc[f][n], af[f], bk0[n]);
            __builtin_amdgcn_s_setprio(0);
            BAR();
        }
        // ===== ph2: MFMA k1 (frags already in regs); stage B0(te); vmcnt(4) =====
        {
            if (!last) {
                STAGE_B(SB0, te);
                asm volatile("s_waitcnt vmcnt(4)" ::: "memory");
            } else {
                asm volatile("s_waitcnt vmcnt(0)" ::: "memory");
            }
            __builtin_amdgcn_s_setprio(1);
            #pragma unroll
            for (int f = 0; f < 4; ++f)
                #pragma unroll
                for (int n = 0; n < 4; ++n) mfma_i8(acc[f][n], af[f + 4], bk1[n]);
            __builtin_amdgcn_s_setprio(0);
            BAR();
        }
        // ===== ph3: read A(buf1, both kf) + all B(buf1); stage A0(te); MFMA k0 =====
        {
            #pragma unroll
            for (int f = 0; f < 4; ++f) {
                af[f]     = *(const i32x4*)&lds[SA1 + aK0 + f * 2048];
                af[f + 4] = *(const i32x4*)&lds[SA1 + aK1 + f * 2048];
            }
            #pragma unroll
            for (int n = 0; n < 4; ++n) {
                bk0[n] = *(const i32x4*)&lds[SB1 + bK0 + n * 2048];
                bk1[n] = *(const i32x4*)&lds[SB1 + bK1 + n * 2048];
            }
            if (!last) STAGE_A(SA0, te);
            __builtin_amdgcn_s_setprio(1);
            #pragma unroll
            for (int f = 0; f < 4; ++f)
                #pragma unroll
                for (int n = 0; n < 4; ++n) mfma_i8(acc[f][n], af[f], bk0[n]);
            __builtin_amdgcn_s_setprio(0);
            BAR();
        }
        // ===== ph4: MFMA k1 (regs); stage B1(to); vmcnt(4) =====
        {
            if (!last) {
                STAGE_B(SB1, to);
                asm volatile("s_waitcnt vmcnt(4)" ::: "memory");
            }
            __builtin_amdgcn_s_setprio(1);
            #pragma unroll
            for (int f = 0; f < 4; ++f)
                #pragma unroll
                for (int n = 0; n < 4; ++n) mfma_i8(acc[f][n], af[f + 4], bk1[n]);
            __builtin_amdgcn_s_setprio(0);
            BAR();
        }
    }

    // ---- epilogue: C/D map col=lane&15, row=(lane>>4)*4+j; dequant ----
    const int row0 = bm * 128 + m_base + (lane >> 4) * 4;
    const int col0 = bn * 128 + n_base + lr;
    #pragma unroll
    for (int f = 0; f < 4; ++f)
        #pragma unroll
        for (int n = 0; n < 4; ++n) {
            const int r = row0 + f * 16;
            const int c = col0 + n * 16;
            #pragma unroll
            for (int j = 0; j < 4; ++j)
                out[(size_t)(r + j) * COUT + c] = QDEQ * (float)acc[f][n][j];
        }
}

// =====================  fallback (tiny ws): bf16 reg-staged  =====================
__global__ void binw_bf16(const float* __restrict__ w, __bf16* __restrict__ wbt) {
    const int cout = threadIdx.x;
    const int rc   = blockIdx.x;
    const float v  = w[(size_t)rc * COUT + cout];
    const float s  = (v > 0.f) ? 1.f : ((v < 0.f) ? -1.f : 0.f);
    wbt[((size_t)((rc >> 8) * COUT + cout)) * CIN + (rc & 255)] = (__bf16)s;
}

__global__ __launch_bounds__(512) void conv_fb(const float* __restrict__ x,
                                               const __bf16* __restrict__ wbt,
                                               float* __restrict__ out) {
    __shared__ __bf16 Alds[128][72];
    __shared__ __bf16 Blds[256][72];
    typedef __bf16 bf8 __attribute__((ext_vector_type(8)));

    const int tid  = threadIdx.x;
    const int lane = tid & 63;
    const int wave = tid >> 6;
    const int m_base = (wave >> 2) * 64;
    const int n_base = (wave & 3) * 64;
    const int lr = lane & 15;
    const int kb = (lane >> 4) * 8;

    const int arow = tid >> 2;
    const int aseg = tid & 3;
    const int p    = blockIdx.x * 128 + arow;
    const int rem  = p % 3136;
    const int h    = rem / 56;
    const int wc   = rem % 56;

    f32x4 acc[4][4];
    #pragma unroll
    for (int i = 0; i < 4; ++i)
        #pragma unroll
        for (int j = 0; j < 4; ++j)
            acc[i][j] = (f32x4){0.f, 0.f, 0.f, 0.f};

    for (int tap = 0; tap < 9; ++tap) {
        const int dh = tap / 3 - 1;
        const int dw = tap % 3 - 1;
        const bool valid = ((unsigned)(h + dh) < 56u) && ((unsigned)(wc + dw) < 56u);
        const long aoff = ((long)p + (long)dh * 56 + dw) * CIN + aseg * 16;
        const __bf16* bsrc = wbt + (size_t)tap * COUT * CIN;

        #pragma unroll
        for (int ks = 0; ks < 4; ++ks) {
            const int c0 = ks * 64;
            __syncthreads();
            f32x4 f0, f1, f2, f3;
            if (valid) {
                const f32x4* s4 = (const f32x4*)(x + aoff + c0);
                f0 = s4[0]; f1 = s4[1]; f2 = s4[2]; f3 = s4[3];
            } else {
                f0 = f1 = f2 = f3 = (f32x4){0.f, 0.f, 0.f, 0.f};
            }
            bf8 v0, v1;
            #pragma unroll
            for (int j = 0; j < 4; ++j) {
                v0[j] = (__bf16)f0[j]; v0[j + 4] = (__bf16)f1[j];
                v1[j] = (__bf16)f2[j]; v1[j + 4] = (__bf16)f3[j];
            }
            *(bf8*)&Alds[arow][aseg * 16]     = v0;
            *(bf8*)&Alds[arow][aseg * 16 + 8] = v1;
            #pragma unroll
            for (int i = 0; i < 4; ++i) {
                const int chunk = tid + i * 512;
                const int row = chunk >> 3;
                const int cs  = chunk & 7;
                *(uint4*)&Blds[row][cs * 8] = *(const uint4*)(bsrc + row * CIN + c0 + cs * 8);
            }
            __syncthreads();

            bf8 af[4][2], bfr[4][2];
            #pragma unroll
            for (int mf = 0; mf < 4; ++mf)
                #pragma unroll
                for (int kf = 0; kf < 2; ++kf)
                    af[mf][kf] = *(const bf8*)&Alds[m_base + mf * 16 + lr][kf * 32 + kb];
            #pragma unroll
            for (int nf = 0; nf < 4; ++nf)
                #pragma unroll
                for (int kf = 0; kf < 2; ++kf)
                    bfr[nf][kf] = *(const bf8*)&Blds[n_base + nf * 16 + lr][kf * 32 + kb];
            #pragma unroll
            for (int kf = 0; kf < 2; ++kf)
                #pragma unroll
                for (int mf = 0; mf < 4; ++mf)
                    #pragma unroll
                    for (int nf = 0; nf < 4; ++nf)
                        acc[mf][nf] = __builtin_amdgcn_mfma_f32_16x16x32_bf16(
                            af[mf][kf], bfr[nf][kf], acc[mf][nf], 0, 0, 0);
        }
    }
    #pragma unroll
    for (int mf = 0; mf < 4; ++mf)
        #pragma unroll
        for (int nf = 0; nf < 4; ++nf) {
            const int r0 = blockIdx.x * 128 + m_base + mf * 16 + (lane >> 4) * 4;
            const int c  = n_base + nf * 16 + lr;
            #pragma unroll
            for (int j = 0; j < 4; ++j)
                out[(size_t)(r0 + j) * COUT + c] = acc[mf][nf][j];
        }
}

extern "C" void kernel_launch(void* const* d_in, const int* in_sizes, int n_in,
                              void* d_out, int out_size, void* d_ws, size_t ws_size,
                              hipStream_t stream) {
    const float* x = (const float*)d_in[0];
    const float* w = (const float*)d_in[1];
    float* out = (float*)d_out;
    char* ws = (char*)d_ws;

    if (ws_size >= WS_NEED_I8) {
        signed char* wbt = (signed char*)(ws + WBT_OFF);
        signed char* xq  = (signed char*)(ws + XQ_OFF);
        prep_kernel<<<13456 + 2304, 256, 0, stream>>>(x, xq, w, wbt);
        conv4i<<<1568, 256, 0, stream>>>(xq, wbt, out);
    } else {
        __bf16* wbt = (__bf16*)(ws + WBT_OFF);
        binw_bf16<<<9 * CIN, COUT, 0, stream>>>(w, wbt);
        conv_fb<<<NPIX / 128, 512, 0, stream>>>(x, wbt, out);
    }
}